// Round 3
// baseline (350.449 us; speedup 1.0000x reference)
//
#include <hip/hip_runtime.h>
#include <hip/hip_fp16.h>

// Problem constants
#define BB 4
#define TT 16
#define HH 512
#define WW 512

// Tile: 256 threads, output 128 wide x 64 tall; thread = 8 wide x 4 tall (16 tx x 16 ty)
#define TW 128
#define TH 64
#define HALO 8
#define SR 80                 // staged rows
#define SCPX 144              // staged pixels per row
#define SA_BYTES 576          // bufA row stride: 144 half2 = 144 dwords (mod 32 == 16)
#define SB_BYTES 320          // bufB row stride: 80 dwords (mod 32 == 16), 72 used
#define BUFA_BYTES (SR * SA_BYTES)   // 46080
#define BUFB_BYTES (SR * SB_BYTES)   // 25600

typedef _Float16 h2_t __attribute__((ext_vector_type(2)));

#if __has_builtin(__builtin_amdgcn_fdot2)
#define FDOT2(a, b, c) __builtin_amdgcn_fdot2((a), (b), (c), false)
#else
#define FDOT2(a, b, c) fmaf((float)((a)[0]), (float)((b)[0]), \
                       fmaf((float)((a)[1]), (float)((b)[1]), (c)))
#endif

__device__ __forceinline__ h2_t as_h2(unsigned int u) {
    union { unsigned int x; h2_t h; } c; c.x = u; return c.h;
}

__device__ __forceinline__ int reflect_idx(int q, int n) {
    q = abs(q);
    if (q >= n) q = 2 * n - 2 - q;
    return q;
}

// pw layout (floats[226], uints bitcast):
//  [0..74]    uint: half2 {s*w[prev], s*w[cur]} per tap (tap = br*25 + i*5 + j)
//  [75..149]  uint: half2 {s*w[next], 0}
//  [150..224] uint: half2 {0, s*w[next]}
//  [225]      float: combined bias = a*b1 + b*b2 + c*b3
__global__ void pack_weights(const float* __restrict__ w1, const float* __restrict__ b1,
                             const float* __restrict__ w2, const float* __restrict__ b2,
                             const float* __restrict__ w3, const float* __restrict__ b3,
                             const float* __restrict__ sa, const float* __restrict__ sb,
                             const float* __restrict__ sc, float* __restrict__ pw) {
    int tid = threadIdx.x;
    float s0 = sa[0], s1 = sb[0], s2 = sc[0];
    unsigned int* pwu = (unsigned int*)pw;
    if (tid < 75) {
        int br = tid / 25;
        int r  = tid % 25;
        float sv = (br == 0) ? s0 : (br == 1) ? s1 : s2;
        const float* wp = (br == 0) ? w1 : (br == 1) ? w2 : w3;
        float wprev = sv * wp[0 * 25 + r];
        float wcur  = sv * wp[1 * 25 + r];
        float wnext = sv * wp[2 * 25 + r];
        union { __half2 h; unsigned int u; } cv;
        cv.h = __floats2half2_rn(wprev, wcur);  pwu[tid]       = cv.u;
        cv.h = __floats2half2_rn(wnext, 0.0f);  pwu[75 + tid]  = cv.u;
        cv.h = __floats2half2_rn(0.0f, wnext);  pwu[150 + tid] = cv.u;
    }
    if (tid == 0) pw[225] = s0 * b1[0] + s1 * b2[0] + s2 * b3[0];
}

__global__ __launch_bounds__(256, 2) void conv_block(const float* __restrict__ x,
                                                     float* __restrict__ out,
                                                     const float* __restrict__ pw) {
    __shared__ char ldsA[BUFA_BYTES];   // half2 {prev, cur} per px
    __shared__ char ldsB[BUFB_BYTES];   // half  {next} per px

    const int bt = blockIdx.z;
    const int t  = bt % TT;
    const int h0 = blockIdx.y * TH;
    const int w0 = blockIdx.x * TW;
    const int tid = threadIdx.x;
    const int tx = tid & 15;
    const int ty = tid >> 4;
    const int oc = tx * 8;
    const int orow = ty * 4;

    const int tprev = (t == 0) ? 1 : t - 1;
    const int tnext = (t == TT - 1) ? TT - 2 : t + 1;
    const int bbase = (bt / TT) * TT;
    const size_t fs = (size_t)HH * WW;
    const float* frp = x + (size_t)(bbase + tprev) * fs;
    const float* frc = x + (size_t)bt * fs;
    const float* frn = x + (size_t)(bbase + tnext) * fs;

    // ---- Stage bufA: {prev,cur} interleaved half2, quad-XOR by row&4 ----
    for (int k = tid; k < SR * 36; k += 256) {
        int row = k / 36;
        int c4  = k - row * 36;
        int gh = reflect_idx(h0 - HALO + row, HH);
        int gb = w0 - HALO + c4 * 4;
        float4 vp, vc;
        if (gb >= 0 && gb + 3 < WW) {
            vp = *reinterpret_cast<const float4*>(frp + (size_t)gh * WW + gb);
            vc = *reinterpret_cast<const float4*>(frc + (size_t)gh * WW + gb);
        } else {
            int g0 = reflect_idx(gb + 0, WW), g1 = reflect_idx(gb + 1, WW);
            int g2 = reflect_idx(gb + 2, WW), g3 = reflect_idx(gb + 3, WW);
            const float* rp = frp + (size_t)gh * WW;
            const float* rc = frc + (size_t)gh * WW;
            vp = make_float4(rp[g0], rp[g1], rp[g2], rp[g3]);
            vc = make_float4(rc[g0], rc[g1], rc[g2], rc[g3]);
        }
        union { __half2 h[4]; uint4 u; } cv;
        cv.h[0] = __floats2half2_rn(vp.x, vc.x);
        cv.h[1] = __floats2half2_rn(vp.y, vc.y);
        cv.h[2] = __floats2half2_rn(vp.z, vc.z);
        cv.h[3] = __floats2half2_rn(vp.w, vc.w);
        int xb4 = (row & 4) << 2;                     // 0 or 16 bytes
        *reinterpret_cast<uint4*>(ldsA + row * SA_BYTES + ((c4 * 16) ^ xb4)) = cv.u;
    }

    // ---- Stage bufB: {next} half, 8 px per 16B quad, quad-XOR by row&4 ----
    for (int k = tid; k < SR * 18; k += 256) {
        int row = k / 18;
        int c8  = k - row * 18;
        int gh = reflect_idx(h0 - HALO + row, HH);
        int gb = w0 - HALO + c8 * 8;
        float4 v0, v1;
        if (gb >= 0 && gb + 7 < WW) {
            v0 = *reinterpret_cast<const float4*>(frn + (size_t)gh * WW + gb);
            v1 = *reinterpret_cast<const float4*>(frn + (size_t)gh * WW + gb + 4);
        } else {
            const float* rn_ = frn + (size_t)gh * WW;
            v0 = make_float4(rn_[reflect_idx(gb + 0, WW)], rn_[reflect_idx(gb + 1, WW)],
                             rn_[reflect_idx(gb + 2, WW)], rn_[reflect_idx(gb + 3, WW)]);
            v1 = make_float4(rn_[reflect_idx(gb + 4, WW)], rn_[reflect_idx(gb + 5, WW)],
                             rn_[reflect_idx(gb + 6, WW)], rn_[reflect_idx(gb + 7, WW)]);
        }
        union { __half2 h[4]; uint4 u; } cv;
        cv.h[0] = __floats2half2_rn(v0.x, v0.y);
        cv.h[1] = __floats2half2_rn(v0.z, v0.w);
        cv.h[2] = __floats2half2_rn(v1.x, v1.y);
        cv.h[3] = __floats2half2_rn(v1.z, v1.w);
        int xb4 = (row & 4) << 2;
        *reinterpret_cast<uint4*>(ldsB + row * SB_BYTES + ((c8 * 16) ^ xb4)) = cv.u;
    }

    const float bias = pw[225];
    float acc[4][8];
#pragma unroll
    for (int p = 0; p < 4; ++p)
#pragma unroll
        for (int q = 0; q < 8; ++q) acc[p][q] = bias;

    __syncthreads();

    const unsigned int* wPC = (const unsigned int*)pw;   // {prev,cur}
    const unsigned int* wNE = wPC + 75;                  // {next,0}  for even half index
    const unsigned int* wNO = wPC + 150;                 // {0,next}  for odd half index

#pragma unroll
    for (int rr = 0; rr < 20; ++rr) {
        const int row = orow + rr;
        const int s = (row & 4) << 2;                    // byte XOR: 0 or 16
        // bufA: logical quad (2tx+q) lives at physical quad (2tx+q)^xb; since 2tx is
        // even, address = base + (16q ^ s). Register mapping stays compile-time.
        const char* pA = ldsA + row * SA_BYTES + tx * 32;
        union { uint4 u[6]; h2_t h[24]; } A;
        A.u[0] = *reinterpret_cast<const uint4*>(pA + ((0)  ^ s));
        A.u[1] = *reinterpret_cast<const uint4*>(pA + ((16) ^ s));
        A.u[2] = *reinterpret_cast<const uint4*>(pA + ((32) ^ s));
        A.u[3] = *reinterpret_cast<const uint4*>(pA + ((48) ^ s));
        A.u[4] = *reinterpret_cast<const uint4*>(pA + ((64) ^ s));
        A.u[5] = *reinterpret_cast<const uint4*>(pA + ((80) ^ s));

        const int xb = (row >> 2) & 1;
        const char* pB = ldsB + row * SB_BYTES;
        union { uint4 u[3]; h2_t h[12]; } Bv;
        Bv.u[0] = *reinterpret_cast<const uint4*>(pB + (((tx + 0) ^ xb) << 4));
        Bv.u[1] = *reinterpret_cast<const uint4*>(pB + (((tx + 1) ^ xb) << 4));
        Bv.u[2] = *reinterpret_cast<const uint4*>(pB + (((tx + 2) ^ xb) << 4));

#pragma unroll
        for (int br = 0; br < 3; ++br) {
            const int d = 1 << br;
#pragma unroll
            for (int i = 0; i < 5; ++i) {
                const int pr = rr - 8 - (i - 2) * d;     // output row fed by this tap row
                if (pr < 0 || pr > 3) continue;          // compile-time fold
#pragma unroll
                for (int j = 0; j < 5; ++j) {
                    const int tap = br * 25 + i * 5 + j;
                    const h2_t wp = as_h2(wPC[tap]);
                    const h2_t we = as_h2(wNE[tap]);
                    const h2_t wo = as_h2(wNO[tap]);
                    const int cb = 8 + (j - 2) * d;
#pragma unroll
                    for (int q = 0; q < 8; ++q) {
                        const int h = cb + q;
                        acc[pr][q] = FDOT2(A.h[h], wp, acc[pr][q]);          // prev+cur
                        const h2_t xn = Bv.h[h >> 1];
                        acc[pr][q] = FDOT2(xn, ((h & 1) ? wo : we), acc[pr][q]);  // next
                    }
                }
            }
        }
    }

    // ---- Epilogue: tanh + fp32 store ----
    float* dst = out + (size_t)bt * fs + (size_t)h0 * WW + w0;
#pragma unroll
    for (int p = 0; p < 4; ++p) {
#pragma unroll
        for (int q = 0; q < 8; ++q) {
            float v = acc[p][q];
            float e = __expf(2.0f * v);
            acc[p][q] = 1.0f - 2.0f / (e + 1.0f);
        }
        float4 v0 = make_float4(acc[p][0], acc[p][1], acc[p][2], acc[p][3]);
        float4 v1 = make_float4(acc[p][4], acc[p][5], acc[p][6], acc[p][7]);
        float* rowp = dst + (size_t)(orow + p) * WW + oc;
        *reinterpret_cast<float4*>(rowp) = v0;
        *reinterpret_cast<float4*>(rowp + 4) = v1;
    }
}

extern "C" void kernel_launch(void* const* d_in, const int* in_sizes, int n_in,
                              void* d_out, int out_size, void* d_ws, size_t ws_size,
                              hipStream_t stream) {
    const float* x = (const float*)d_in[0];
    float* pw1 = (float*)d_ws;
    float* pw2 = (float*)d_ws + 256;
    float* y   = (float*)((char*)d_ws + 4096);   // intermediate, 64 MB
    float* z   = (float*)d_out;

    pack_weights<<<1, 256, 0, stream>>>((const float*)d_in[1], (const float*)d_in[2],
                                        (const float*)d_in[3], (const float*)d_in[4],
                                        (const float*)d_in[5], (const float*)d_in[6],
                                        (const float*)d_in[7], (const float*)d_in[8],
                                        (const float*)d_in[9], pw1);
    pack_weights<<<1, 256, 0, stream>>>((const float*)d_in[10], (const float*)d_in[11],
                                        (const float*)d_in[12], (const float*)d_in[13],
                                        (const float*)d_in[14], (const float*)d_in[15],
                                        (const float*)d_in[16], (const float*)d_in[17],
                                        (const float*)d_in[18], pw2);

    dim3 grid(WW / TW, HH / TH, BB * TT);
    conv_block<<<grid, 256, 0, stream>>>(x, y, pw1);
    conv_block<<<grid, 256, 0, stream>>>(y, z, pw2);
}